// Round 4
// baseline (271.900 us; speedup 1.0000x reference)
//
#include <hip/hip_runtime.h>
#include <hip/hip_fp16.h>
#include <cstdint>
#include <cstddef>

#define B_ 512
#define T_ 256
#define N_ 128
#define H_ 64
#define G_ 256  // 4H

typedef __attribute__((ext_vector_type(8))) short short8;
typedef __attribute__((ext_vector_type(4))) float f32x4;

static __device__ __forceinline__ unsigned short f2bf(float f) {
    union { float f; unsigned int i; } v;
    v.f = f;
    unsigned int x = v.i;
    return (unsigned short)((x + 0x7fffu + ((x >> 16) & 1u)) >> 16);  // RNE
}

// ---------------------------------------------------------------------------
// K1+K2 fused: per-batch block (512 blocks, 256 threads).
// Phase A: a[n] = softmax_n( sum_t x[b][t][n]*aw2[t] )  (kept in LDS)
// Phase B: iw = a*x (f32, exact) -> d_out; gatesx = iw@W_ih^T + bias (f16) -> ws
// LDS 80.9 KB -> 2 blocks/CU.
// ---------------------------------------------------------------------------
__global__ __launch_bounds__(256) void k_awgemm(const float* __restrict__ x,
                                                const float* __restrict__ attn_w,
                                                const float* __restrict__ W_ih,
                                                const float* __restrict__ b_ih,
                                                const float* __restrict__ b_hh,
                                                float* __restrict__ iw,
                                                _Float16* __restrict__ gatesx) {
    __shared__ __align__(16) unsigned short Wl[G_][136];  // bf16 W_ih, padded
    __shared__ __align__(16) unsigned short Al[32][136];  // bf16 wx tile (overlaid: red)
    __shared__ float bias[G_];
    __shared__ float aw_s[T_];
    __shared__ float a_s[N_];
    __shared__ float wred[4];
    const int tid = threadIdx.x;
    const int b = blockIdx.x;

    // ---- stage W_ih (f32 -> bf16), bias, attention weights ----
    for (int q = tid; q < G_ * 32; q += 256) {
        int r = q >> 5, c4 = (q & 31) << 2;
        float4 v = *(const float4*)(W_ih + r * N_ + c4);
        Wl[r][c4 + 0] = f2bf(v.x); Wl[r][c4 + 1] = f2bf(v.y);
        Wl[r][c4 + 2] = f2bf(v.z); Wl[r][c4 + 3] = f2bf(v.w);
    }
    bias[tid] = b_ih[tid] + b_hh[tid];
    aw_s[tid] = attn_w[2 * H_ + tid];
    __syncthreads();

    // ---- Phase A: attention softmax (softmax shift-invariance kills h/c/bias) ----
    float (*red)[128] = (float(*)[128])&Al[0][0];  // overlay (Al unused yet)
    const int n0 = (tid & 31) << 2;
    const int tg = tid >> 5;
    const float* xb = x + (size_t)b * (T_ * N_);
    {
        float p0 = 0.f, p1 = 0.f, p2 = 0.f, p3 = 0.f;
        for (int t = tg; t < T_; t += 8) {
            float4 v = *(const float4*)(xb + t * N_ + n0);
            float w = aw_s[t];
            p0 += v.x * w; p1 += v.y * w; p2 += v.z * w; p3 += v.w * w;
        }
        red[tg][n0 + 0] = p0; red[tg][n0 + 1] = p1;
        red[tg][n0 + 2] = p2; red[tg][n0 + 3] = p3;
    }
    __syncthreads();
    {
        float s = 0.f;
        if (tid < 128) {
            #pragma unroll
            for (int g = 0; g < 8; ++g) s += red[g][tid];
        }
        float m = (tid < 128) ? s : -1e30f;
        #pragma unroll
        for (int d = 1; d < 64; d <<= 1) m = fmaxf(m, __shfl_xor(m, d));
        if ((tid & 63) == 0) wred[tid >> 6] = m;
        __syncthreads();
        m = fmaxf(wred[0], wred[1]);
        __syncthreads();
        float e = (tid < 128) ? __expf(s - m) : 0.f;
        float z = e;
        #pragma unroll
        for (int d = 1; d < 64; d <<= 1) z += __shfl_xor(z, d);
        if ((tid & 63) == 0) wred[tid >> 6] = z;
        __syncthreads();
        z = wred[0] + wred[1];
        if (tid < 128) a_s[tid] = e / z;
    }
    __syncthreads();   // a_s ready; red dead -> Al reusable

    // ---- Phase B: weighting + GEMM (proven MFMA tile) ----
    const int lane = tid & 63;
    const int lr = lane & 15;
    const int lk = (lane >> 4) << 3;
    const int gc0 = (tid >> 6) << 6;     // wave's gate-column base
    const int orow = (lane >> 4) << 2;

    for (int st = 0; st < 8; ++st) {
        const int r0 = b * T_ + st * 32;
        __syncthreads();
        for (int q = tid; q < 32 * 32; q += 256) {
            int r = q >> 5, c4 = (q & 31) << 2;
            size_t off = (size_t)(r0 + r) * N_ + c4;
            float4 v = *(const float4*)(x + off);
            float4 w;
            w.x = a_s[c4 + 0] * v.x; w.y = a_s[c4 + 1] * v.y;
            w.z = a_s[c4 + 2] * v.z; w.w = a_s[c4 + 3] * v.w;
            *(float4*)(iw + off) = w;            // output 0 (f32, exact)
            Al[r][c4 + 0] = f2bf(w.x); Al[r][c4 + 1] = f2bf(w.y);
            Al[r][c4 + 2] = f2bf(w.z); Al[r][c4 + 3] = f2bf(w.w);
        }
        __syncthreads();

        f32x4 acc[2][4];
        #pragma unroll
        for (int mt = 0; mt < 2; ++mt)
            #pragma unroll
            for (int nt = 0; nt < 4; ++nt)
                acc[mt][nt] = (f32x4){0.f, 0.f, 0.f, 0.f};

        #pragma unroll
        for (int kk = 0; kk < N_; kk += 32) {
            short8 af0 = *(const short8*)(&Al[lr][kk + lk]);
            short8 af1 = *(const short8*)(&Al[16 + lr][kk + lk]);
            #pragma unroll
            for (int nt = 0; nt < 4; ++nt) {
                short8 bfv = *(const short8*)(&Wl[gc0 + nt * 16 + lr][kk + lk]);
                acc[0][nt] = __builtin_amdgcn_mfma_f32_16x16x32_bf16(af0, bfv, acc[0][nt], 0, 0, 0);
                acc[1][nt] = __builtin_amdgcn_mfma_f32_16x16x32_bf16(af1, bfv, acc[1][nt], 0, 0, 0);
            }
        }
        // D: col = gc0+nt*16+lr, row = mt*16+(lane>>4)*4+reg
        #pragma unroll
        for (int mt = 0; mt < 2; ++mt) {
            #pragma unroll
            for (int nt = 0; nt < 4; ++nt) {
                int col = gc0 + nt * 16 + lr;
                float bs = bias[col];
                #pragma unroll
                for (int rg = 0; rg < 4; ++rg) {
                    int rr = r0 + mt * 16 + orow + rg;
                    gatesx[(size_t)rr * G_ + col] = (_Float16)(acc[mt][nt][rg] + bs);
                }
            }
        }
    }
}

// ---------------------------------------------------------------------------
// K3: LSTM recurrence, VALU form. 512 blocks (1 batch each), 256 threads.
// Thread g owns gate column g: W_hh[g][:] in 64 VGPRs. h broadcast via
// UNIFORM-address LDS float4 reads (bank-broadcast, conflict-free).
// Cell math on lanes 0..63 only. 2 barriers/step.
// __launch_bounds__(256, 2): min 2 waves/EU -> VGPR cap 256, so wr[64] stays
// register-resident (round-3 run at default bounds gave VGPR_Count=52 < 64:
// W_hh provably spilled, 131 KB/step/CU reload ~= the whole 242 us).
// ---------------------------------------------------------------------------
__global__ __launch_bounds__(256, 2) void k_rnn2(const _Float16* __restrict__ gatesx,
                                                 const float* __restrict__ W_hh,
                                                 float* __restrict__ enc) {
    __shared__ __align__(16) float hb[H_];
    __shared__ float gl[G_];
    const int tid = threadIdx.x;
    const int b = blockIdx.x;

    float wr[H_];
    #pragma unroll
    for (int j = 0; j < H_; j += 4) {
        float4 v = *(const float4*)(W_hh + tid * H_ + j);
        wr[j + 0] = v.x; wr[j + 1] = v.y; wr[j + 2] = v.z; wr[j + 3] = v.w;
    }
    if (tid < H_) hb[tid] = 0.f;
    float c = 0.f;

    const _Float16* gx = gatesx + (size_t)b * T_ * G_;
    float gcur = (float)gx[tid];   // t = 0
    __syncthreads();

    for (int t = 0; t < T_; ++t) {
        // prefetch next step's gate input (coalesced 512B per wave-pair)
        _Float16 gn = gx[(size_t)(t + 1 < T_ ? t + 1 : t) * G_ + tid];

        float a0 = gcur, a1 = 0.f, a2 = 0.f, a3 = 0.f;
        const float4* h4 = (const float4*)hb;
        #pragma unroll
        for (int jj = 0; jj < 16; ++jj) {
            float4 hv = h4[jj];                 // uniform address -> broadcast
            a0 += hv.x * wr[4 * jj + 0];
            a1 += hv.y * wr[4 * jj + 1];
            a2 += hv.z * wr[4 * jj + 2];
            a3 += hv.w * wr[4 * jj + 3];
        }
        gl[tid] = (a0 + a1) + (a2 + a3);
        __syncthreads();

        if (tid < H_) {
            float ig = gl[tid], fg = gl[H_ + tid], gg = gl[2 * H_ + tid], og = gl[3 * H_ + tid];
            float si = 1.f / (1.f + __expf(-ig));
            float sf = 1.f / (1.f + __expf(-fg));
            float so = 1.f / (1.f + __expf(-og));
            float tg = 1.f - 2.f / (__expf(2.f * gg) + 1.f);   // tanh
            c = sf * c + si * tg;
            float tc = 1.f - 2.f / (__expf(2.f * c) + 1.f);    // tanh
            float h = so * tc;
            hb[tid] = h;
            enc[((size_t)b * T_ + t) * H_ + tid] = h;
        }
        __syncthreads();
        gcur = (float)gn;
    }
}

extern "C" void kernel_launch(void* const* d_in, const int* in_sizes, int n_in,
                              void* d_out, int out_size, void* d_ws, size_t ws_size,
                              hipStream_t stream) {
    if (n_in < 7 || in_sizes[0] != B_ * T_ * N_) return;

    const float* x    = (const float*)d_in[0];
    const float* aw   = (const float*)d_in[1];
    // d_in[2] (attn_b) provably cancels in the softmax — unused.
    const float* W_ih = (const float*)d_in[3];
    const float* W_hh = (const float*)d_in[4];
    const float* b_ih = (const float*)d_in[5];
    const float* b_hh = (const float*)d_in[6];

    float* iwp = (float*)d_out;                          // (B,T,N) f32
    float* enc = (float*)d_out + (size_t)B_ * T_ * N_;   // (B,T,H) f32

    _Float16* gatesx = (_Float16*)d_ws;                  // B*T*G f16
    size_t need = (size_t)B_ * T_ * G_ * sizeof(_Float16);
    if (ws_size < need) return;  // fail loudly rather than corrupt

    hipLaunchKernelGGL(k_awgemm, dim3(B_), dim3(256), 0, stream,
                       x, aw, W_ih, b_ih, b_hh, iwp, gatesx);
    hipLaunchKernelGGL(k_rnn2, dim3(B_), dim3(256), 0, stream, gatesx, W_hh, enc);
}

// Round 5
// 185.215 us; speedup vs baseline: 1.4680x; 1.4680x over previous
//
#include <hip/hip_runtime.h>
#include <hip/hip_fp16.h>
#include <cstdint>
#include <cstddef>

#define B_ 512
#define T_ 256
#define N_ 128
#define H_ 64
#define G_ 256  // 4H

typedef __attribute__((ext_vector_type(8))) short short8;
typedef __attribute__((ext_vector_type(4))) float f32x4;
typedef _Float16 half2_t __attribute__((ext_vector_type(2)));

static __device__ __forceinline__ unsigned short f2bf(float f) {
    union { float f; unsigned int i; } v;
    v.f = f;
    unsigned int x = v.i;
    return (unsigned short)((x + 0x7fffu + ((x >> 16) & 1u)) >> 16);  // RNE
}
static __device__ __forceinline__ half2_t u2h2(unsigned int u) {
    union { unsigned int u; half2_t h; } v; v.u = u; return v.h;
}
static __device__ __forceinline__ unsigned int h2u(half2_t h) {
    union { half2_t h; unsigned int u; } v; v.h = h; return v.u;
}

// ---------------------------------------------------------------------------
// K1+K2 fused: per-batch block (512 blocks, 256 threads).
// Phase A: a[n] = softmax_n( sum_t x[b][t][n]*aw2[t] )  (kept in LDS)
// Phase B: iw = a*x (f32, exact) -> d_out; gatesx = iw@W_ih^T + bias (f16) -> ws
// ---------------------------------------------------------------------------
__global__ __launch_bounds__(256) void k_awgemm(const float* __restrict__ x,
                                                const float* __restrict__ attn_w,
                                                const float* __restrict__ W_ih,
                                                const float* __restrict__ b_ih,
                                                const float* __restrict__ b_hh,
                                                float* __restrict__ iw,
                                                _Float16* __restrict__ gatesx) {
    __shared__ __align__(16) unsigned short Wl[G_][136];  // bf16 W_ih, padded
    __shared__ __align__(16) unsigned short Al[32][136];  // bf16 wx tile (overlaid: red)
    __shared__ float bias[G_];
    __shared__ float aw_s[T_];
    __shared__ float a_s[N_];
    __shared__ float wred[4];
    const int tid = threadIdx.x;
    const int b = blockIdx.x;

    for (int q = tid; q < G_ * 32; q += 256) {
        int r = q >> 5, c4 = (q & 31) << 2;
        float4 v = *(const float4*)(W_ih + r * N_ + c4);
        Wl[r][c4 + 0] = f2bf(v.x); Wl[r][c4 + 1] = f2bf(v.y);
        Wl[r][c4 + 2] = f2bf(v.z); Wl[r][c4 + 3] = f2bf(v.w);
    }
    bias[tid] = b_ih[tid] + b_hh[tid];
    aw_s[tid] = attn_w[2 * H_ + tid];
    __syncthreads();

    // ---- Phase A: attention softmax (shift-invariance kills h/c/bias) ----
    float (*red)[128] = (float(*)[128])&Al[0][0];
    const int n0 = (tid & 31) << 2;
    const int tg = tid >> 5;
    const float* xb = x + (size_t)b * (T_ * N_);
    {
        float p0 = 0.f, p1 = 0.f, p2 = 0.f, p3 = 0.f;
        for (int t = tg; t < T_; t += 8) {
            float4 v = *(const float4*)(xb + t * N_ + n0);
            float w = aw_s[t];
            p0 += v.x * w; p1 += v.y * w; p2 += v.z * w; p3 += v.w * w;
        }
        red[tg][n0 + 0] = p0; red[tg][n0 + 1] = p1;
        red[tg][n0 + 2] = p2; red[tg][n0 + 3] = p3;
    }
    __syncthreads();
    {
        float s = 0.f;
        if (tid < 128) {
            #pragma unroll
            for (int g = 0; g < 8; ++g) s += red[g][tid];
        }
        float m = (tid < 128) ? s : -1e30f;
        #pragma unroll
        for (int d = 1; d < 64; d <<= 1) m = fmaxf(m, __shfl_xor(m, d));
        if ((tid & 63) == 0) wred[tid >> 6] = m;
        __syncthreads();
        m = fmaxf(wred[0], wred[1]);
        __syncthreads();
        float e = (tid < 128) ? __expf(s - m) : 0.f;
        float z = e;
        #pragma unroll
        for (int d = 1; d < 64; d <<= 1) z += __shfl_xor(z, d);
        if ((tid & 63) == 0) wred[tid >> 6] = z;
        __syncthreads();
        z = wred[0] + wred[1];
        if (tid < 128) a_s[tid] = e / z;
    }
    __syncthreads();

    // ---- Phase B: weighting + GEMM ----
    const int lane = tid & 63;
    const int lr = lane & 15;
    const int lk = (lane >> 4) << 3;
    const int gc0 = (tid >> 6) << 6;
    const int orow = (lane >> 4) << 2;

    for (int st = 0; st < 8; ++st) {
        const int r0 = b * T_ + st * 32;
        __syncthreads();
        for (int q = tid; q < 32 * 32; q += 256) {
            int r = q >> 5, c4 = (q & 31) << 2;
            size_t off = (size_t)(r0 + r) * N_ + c4;
            float4 v = *(const float4*)(x + off);
            float4 w;
            w.x = a_s[c4 + 0] * v.x; w.y = a_s[c4 + 1] * v.y;
            w.z = a_s[c4 + 2] * v.z; w.w = a_s[c4 + 3] * v.w;
            *(float4*)(iw + off) = w;
            Al[r][c4 + 0] = f2bf(w.x); Al[r][c4 + 1] = f2bf(w.y);
            Al[r][c4 + 2] = f2bf(w.z); Al[r][c4 + 3] = f2bf(w.w);
        }
        __syncthreads();

        f32x4 acc[2][4];
        #pragma unroll
        for (int mt = 0; mt < 2; ++mt)
            #pragma unroll
            for (int nt = 0; nt < 4; ++nt)
                acc[mt][nt] = (f32x4){0.f, 0.f, 0.f, 0.f};

        #pragma unroll
        for (int kk = 0; kk < N_; kk += 32) {
            short8 af0 = *(const short8*)(&Al[lr][kk + lk]);
            short8 af1 = *(const short8*)(&Al[16 + lr][kk + lk]);
            #pragma unroll
            for (int nt = 0; nt < 4; ++nt) {
                short8 bfv = *(const short8*)(&Wl[gc0 + nt * 16 + lr][kk + lk]);
                acc[0][nt] = __builtin_amdgcn_mfma_f32_16x16x32_bf16(af0, bfv, acc[0][nt], 0, 0, 0);
                acc[1][nt] = __builtin_amdgcn_mfma_f32_16x16x32_bf16(af1, bfv, acc[1][nt], 0, 0, 0);
            }
        }
        #pragma unroll
        for (int mt = 0; mt < 2; ++mt) {
            #pragma unroll
            for (int nt = 0; nt < 4; ++nt) {
                int col = gc0 + nt * 16 + lr;
                float bs = bias[col];
                #pragma unroll
                for (int rg = 0; rg < 4; ++rg) {
                    int rr = r0 + mt * 16 + orow + rg;
                    gatesx[(size_t)rr * G_ + col] = (_Float16)(acc[mt][nt][rg] + bs);
                }
            }
        }
    }
}

// ---------------------------------------------------------------------------
// K3: LSTM recurrence. 512 blocks (1 batch), 256 threads.
// Thread g owns gate row g as 32x half2 (32 VGPRs) -> v_dot2_f32_f16.
// Round-4 lesson: launch_bounds(256,2) does NOT stop the scheduler from
// targeting 8 waves/EU and sinking a 64-VGPR weight array into the loop
// (VGPR_Count stayed 52, dur 242us = per-step W reload at L2 BW). Fix:
// (a) halve footprint via packed f16 dot2, (b) amdgpu_waves_per_eu(2,4)
// caps the occupancy target -> >=128 VGPR budget, (c) asm pin vs remat.
// Per-thread activation (wave-uniform sigmoid/tanh) before the barrier;
// lane<64 tail is just fma + tanh + mul. h kept f16 in LDS (8x b128 bcast).
// ---------------------------------------------------------------------------
__global__ __attribute__((amdgpu_flat_work_group_size(256, 256)))
__attribute__((amdgpu_waves_per_eu(2, 4)))
void k_rnn3(const _Float16* __restrict__ gatesx,
            const float* __restrict__ W_hh,
            float* __restrict__ enc) {
    __shared__ __align__(16) _Float16 hb[H_];   // h_t, f16, 128 B
    __shared__ float act[G_];                   // activated gates
    const int tid = threadIdx.x;
    const int b = blockIdx.x;
    const int wv = tid >> 6;

    // W_hh row g -> 32 packed half2 (f32 source, one-time convert)
    half2_t w2[32];
    #pragma unroll
    for (int q = 0; q < 8; ++q) {
        float4 v0 = *(const float4*)(W_hh + tid * H_ + q * 8);
        float4 v1 = *(const float4*)(W_hh + tid * H_ + q * 8 + 4);
        w2[4 * q + 0] = (half2_t){(_Float16)v0.x, (_Float16)v0.y};
        w2[4 * q + 1] = (half2_t){(_Float16)v0.z, (_Float16)v0.w};
        w2[4 * q + 2] = (half2_t){(_Float16)v1.x, (_Float16)v1.y};
        w2[4 * q + 3] = (half2_t){(_Float16)v1.z, (_Float16)v1.w};
    }
    // pin: forbid rematerialization/sinking of the weight registers
    #pragma unroll
    for (int k = 0; k < 32; ++k) {
        unsigned int u = h2u(w2[k]);
        asm volatile("" : "+v"(u));
        w2[k] = u2h2(u);
    }

    if (tid < 32) ((unsigned int*)hb)[tid] = 0u;   // h_{-1} = 0
    float c = 0.f;

    const _Float16* gx = gatesx + (size_t)b * T_ * G_ + tid;
    float gcur = (float)gx[0];
    __syncthreads();

    for (int t = 0; t < T_; ++t) {
        // prefetch next step's gate input (hides HBM/L2 latency under the step)
        _Float16 gn = gx[(size_t)(t + 1 < T_ ? t + 1 : t) * G_];

        float acc = gcur;
        const uint4* hv = (const uint4*)hb;     // uniform-address broadcast reads
        #pragma unroll
        for (int q = 0; q < 8; ++q) {
            uint4 ch = hv[q];
            acc = __builtin_amdgcn_fdot2(w2[4 * q + 0], u2h2(ch.x), acc, false);
            acc = __builtin_amdgcn_fdot2(w2[4 * q + 1], u2h2(ch.y), acc, false);
            acc = __builtin_amdgcn_fdot2(w2[4 * q + 2], u2h2(ch.z), acc, false);
            acc = __builtin_amdgcn_fdot2(w2[4 * q + 3], u2h2(ch.w), acc, false);
        }
        // per-gate activation, wave-uniform branch (gate order i,f,g,o)
        float a;
        if (wv == 2) a = 1.f - 2.f / (__expf(2.f * acc) + 1.f);   // tanh(g)
        else         a = 1.f / (1.f + __expf(-acc));              // sigmoid(i,f,o)
        act[tid] = a;
        __syncthreads();

        if (tid < H_) {
            float ai = act[tid], af = act[H_ + tid], ag = act[2 * H_ + tid], ao = act[3 * H_ + tid];
            c = af * c + ai * ag;
            float tc = 1.f - 2.f / (__expf(2.f * c) + 1.f);       // tanh(c)
            float h = ao * tc;
            hb[tid] = (_Float16)h;
            enc[((size_t)b * T_ + t) * H_ + tid] = h;
        }
        __syncthreads();
        gcur = (float)gn;
    }
}

extern "C" void kernel_launch(void* const* d_in, const int* in_sizes, int n_in,
                              void* d_out, int out_size, void* d_ws, size_t ws_size,
                              hipStream_t stream) {
    if (n_in < 7 || in_sizes[0] != B_ * T_ * N_) return;

    const float* x    = (const float*)d_in[0];
    const float* aw   = (const float*)d_in[1];
    // d_in[2] (attn_b) provably cancels in the softmax — unused.
    const float* W_ih = (const float*)d_in[3];
    const float* W_hh = (const float*)d_in[4];
    const float* b_ih = (const float*)d_in[5];
    const float* b_hh = (const float*)d_in[6];

    float* iwp = (float*)d_out;                          // (B,T,N) f32
    float* enc = (float*)d_out + (size_t)B_ * T_ * N_;   // (B,T,H) f32

    _Float16* gatesx = (_Float16*)d_ws;                  // B*T*G f16
    size_t need = (size_t)B_ * T_ * G_ * sizeof(_Float16);
    if (ws_size < need) return;  // fail loudly rather than corrupt

    hipLaunchKernelGGL(k_awgemm, dim3(B_), dim3(256), 0, stream,
                       x, aw, W_ih, b_ih, b_hh, iwp, gatesx);
    hipLaunchKernelGGL(k_rnn3, dim3(B_), dim3(256), 0, stream, gatesx, W_hh, enc);
}